// Round 4
// baseline (771.007 us; speedup 1.0000x reference)
//
#include <hip/hip_runtime.h>

// LSTM (B=2048, T=1024, I=8, H=64) + sigmoid(FC), bf16 MFMA — HALF-STEP
// P/Q SOFTWARE PIPELINE.
//
// Diagnosis from r0/r3 counters: MFMA pipe (424 cy) + VALU (641 cy) sum to
// the 1116-cy step wall -> the phases are serialized; overlap never happens
// because each step's dependency chain (gates->act->h->barrier) leaves the
// scheduler nothing independent. Fix: R=8 rows/block, two chain sets
// P (rows 0-3) / Q (rows 4-7) offset by HALF a step. Each half-step body:
//   ds_read fh(S) -> issue 8 h-MFMAs(S)        (pipe crunches ~233 cy)
//   act(other set) (~250 cy VALU)              <- overlaps the MFMA pipe
//   write h(other), re-seed other's x-MFMAs, barrier
// MFMA:VALU overlap is structural, not scheduler luck. h_lds is SINGLE
// buffered: each set's read of h(t-1) and write of h(t) are separated by a
// barrier by the phase structure itself.
//
// grid 256 = 1 block/CU, 2048 light barriers. HP=80 kept (bank conflicts
// 1.88e7->2.0e6 verified). __expf activations + manual f2bf kept (r2 showed
// exp2f lowers to slow ocml; these are the r0-proven versions).

namespace {
constexpr int T_LEN = 1024;
constexpr int R     = 8;    // batch rows per block: P=0..3, Q=4..7
constexpr int TS    = 32;   // timesteps of x per staged chunk
constexpr int HP    = 80;   // h_lds row stride in shorts (160 B)

typedef __attribute__((ext_vector_type(8))) short  short8v;
typedef __attribute__((ext_vector_type(4))) float  float4v;
typedef unsigned short u16;
typedef unsigned long long u64;

__device__ __forceinline__ float fsig(float x) {
  return __builtin_amdgcn_rcpf(1.f + __expf(-x));
}
__device__ __forceinline__ float ftanh(float x) {
  return 1.f - 2.f * __builtin_amdgcn_rcpf(__expf(2.f * x) + 1.f);
}
__device__ __forceinline__ u16 f2bf(float f) {  // RNE
  unsigned int u = __float_as_uint(f);
  unsigned int r = ((u >> 16) & 1u) + 0x7fffu;
  return (u16)((u + r) >> 16);
}

__global__ __launch_bounds__(256, 1) void lstm_pipe(
    const float* __restrict__ x,     // [B, T, 8]
    const float* __restrict__ W_ih,  // [256, 8]
    const float* __restrict__ W_hh,  // [256, 64]
    const float* __restrict__ b_ih,  // [256]
    const float* __restrict__ b_hh,  // [256]
    const float* __restrict__ fc_w,  // [64]
    const float* __restrict__ fc_b,  // [1]
    float* __restrict__ out) {       // [B]
  __shared__ __align__(16) u16   x_lds[2][TS][R][32];  // 32 KB
  __shared__ __align__(16) u16   h_lds[R][HP];         // single buffer!
  __shared__ __align__(16) float hf[R][64];            // final h (fp32)

  const int tid  = threadIdx.x;
  const int lane = tid & 63;
  const int wv   = tid >> 6;       // wave 0..3
  const int g4   = lane >> 4;      // MFMA k-quad / C row-quad
  const int nib  = lane & 15;      // MFMA m/n coord
  const int rowP = nib & 3;        // set P batch row (4x col duplication)
  const int rowQ = 4 + rowP;       // set Q batch row
  const int rsel = nib >> 2;       // which acc reg this thread activates
  const int jh   = 16 * wv + 4 * g4 + rsel;  // owned h index
  const int bBase = blockIdx.x * R;

  // ---- static A fragments: wave wv holds gate tiles {4g+wv}, shared P/Q ----
  short8v a0[4], a1[4], a2[4];
  for (int g = 0; g < 4; ++g) {
    const int n = 64 * g + 16 * wv + nib;  // gate row
    short8v f0, f1, f2;
    for (int j = 0; j < 8; ++j) {
      const int k = 8 * g4 + j;
      float v0 = 0.f;
      if (k < 8) v0 = W_ih[n * 8 + k];
      else if (k == 8) v0 = b_ih[n] + b_hh[n];
      f0[j] = (short)f2bf(v0);
      f1[j] = (short)f2bf(W_hh[n * 64 + k]);
      f2[j] = (short)f2bf(W_hh[n * 64 + 32 + k]);
    }
    a0[g] = f0; a1[g] = f1; a2[g] = f2;
  }

  // ---- LDS init: h0 = 0; x constant channels (bias=1.0, pad=0) per buf ----
  for (int i = tid; i < R * HP; i += 256) ((u16*)h_lds)[i] = 0;
  for (int idx = tid; idx < 2 * TS * R; idx += 256) {
    const int buf = idx >> 8, rem = idx & 255, tt = rem >> 3, rr = rem & 7;
    u16* p = &x_lds[buf][tt][rr][0];
    p[8] = 0x3f80;  // bias channel = 1.0
    for (int chn = 9; chn < 32; ++chn) p[chn] = 0;
  }

  // ---- x staging: 2 float4/thread/chunk (8 KB/chunk), double-buffered ----
  float4v xrA, xrB;
  const int sr = tid >> 5, sm = tid & 31;          // src row, float4 idx base
  const int m1 = sm, m2 = sm + 32;
  const int tt1 = m1 >> 1, ch1 = (m1 & 1) * 4;
  const int tt2 = m2 >> 1, ch2 = (m2 & 1) * 4;
  auto stage_load = [&](int chunk) {
    const float* src = x + ((size_t)bBase + sr) * (T_LEN * 8) +
                       (size_t)chunk * (TS * 8);
    xrA = *(const float4v*)&src[m1 * 4];
    xrB = *(const float4v*)&src[m2 * 4];
  };
  auto stage_write = [&](int buf) {
    union { u64 u; u16 s[4]; } p;
    p.s[0] = f2bf(xrA[0]); p.s[1] = f2bf(xrA[1]);
    p.s[2] = f2bf(xrA[2]); p.s[3] = f2bf(xrA[3]);
    *(u64*)&x_lds[buf][tt1][sr][ch1] = p.u;
    p.s[0] = f2bf(xrB[0]); p.s[1] = f2bf(xrB[1]);
    p.s[2] = f2bf(xrB[2]); p.s[3] = f2bf(xrB[3]);
    *(u64*)&x_lds[buf][tt2][sr][ch2] = p.u;
  };

  stage_load(0);
  stage_write(0);
  __syncthreads();

  const bool sel1 = (rsel & 1) != 0;
  const bool sel2 = (rsel & 2) != 0;
  float cP = 0.f, cQ = 0.f;
  float4v accP[4], accQ[4];

  // acc = x-projection (W_ih + bias), C=0
  auto mfma_x = [&](const u16* xrow, float4v* acc) {
    const short8v fx = *(const short8v*)(xrow + 8 * g4);
#pragma unroll
    for (int g = 0; g < 4; ++g)
      acc[g] = __builtin_amdgcn_mfma_f32_16x16x32_bf16(
          a0[g], fx, (float4v){0.f, 0.f, 0.f, 0.f}, 0, 0, 0);
  };
  // acc += W_hh * h  (8 MFMAs)
  auto mfma_h = [&](const u16* hrow, float4v* acc) {
    const short8v fh0 = *(const short8v*)(hrow + 8 * g4);
    const short8v fh1 = *(const short8v*)(hrow + 32 + 8 * g4);
#pragma unroll
    for (int g = 0; g < 4; ++g)
      acc[g] = __builtin_amdgcn_mfma_f32_16x16x32_bf16(a1[g], fh0, acc[g], 0, 0, 0);
#pragma unroll
    for (int g = 0; g < 4; ++g)
      acc[g] = __builtin_amdgcn_mfma_f32_16x16x32_bf16(a2[g], fh1, acc[g], 0, 0, 0);
  };
  // select this thread's element + LSTM cell update, returns h
  auto act = [&](const float4v* acc, float& c) -> float {
    float gsel[4];
#pragma unroll
    for (int g = 0; g < 4; ++g) {
      const float x01 = sel1 ? acc[g][1] : acc[g][0];
      const float x23 = sel1 ? acc[g][3] : acc[g][2];
      gsel[g] = sel2 ? x23 : x01;
    }
    const float iv = fsig(gsel[0]);
    const float fv = fsig(gsel[1]);
    const float gv = ftanh(gsel[2]);
    const float ov = fsig(gsel[3]);
    c = fv * c + iv * gv;
    return ov * ftanh(c);
  };

  // ---- pipeline prologue: seed accP(0); peeled P-body(0) ----
  mfma_x(&x_lds[0][0][rowP][0], accP);
  mfma_h(&h_lds[rowP][0], accP);        // h(-1)=0: adds nothing, fills pipe
  mfma_x(&x_lds[0][0][rowQ][0], accQ);  // seed accQ(0)
  __syncthreads();

  for (int ch = 0; ch < T_LEN / TS; ++ch) {
    const int xb = ch & 1;
    const bool more = (ch < T_LEN / TS - 1);
#pragma unroll
    for (int tt = 0; tt < TS; ++tt) {
      const bool last = (!more) && (tt == TS - 1);  // t == 1023

      // ======== Q-body(t): h-MFMAs Q(t)  ||  act P(t) ========
      if (tt == 0 && more) stage_load(ch + 1);
      mfma_h(&h_lds[rowQ][0], accQ);
      {
        const float hP = act(accP, cP);
        if (last) hf[rowP][jh] = hP;
        else      h_lds[rowP][jh] = f2bf(hP);
      }
      if (tt < TS - 1) mfma_x(&x_lds[xb][tt + 1][rowP][0], accP);  // seed P(t+1)
      if (tt == TS - 1 && more) stage_write(xb ^ 1);
      __syncthreads();

      // ======== P-body(t+1): h-MFMAs P(t+1)  ||  act Q(t) ========
      if (!last) {
        if (tt == TS - 1) mfma_x(&x_lds[xb ^ 1][0][rowP][0], accP);  // deferred seed
        mfma_h(&h_lds[rowP][0], accP);
        {
          const float hQ = act(accQ, cQ);
          h_lds[rowQ][jh] = f2bf(hQ);
        }
        const u16* qx = (tt < TS - 1) ? &x_lds[xb][tt + 1][rowQ][0]
                                      : &x_lds[xb ^ 1][0][rowQ][0];
        mfma_x(qx, accQ);  // seed Q(t+1)
        __syncthreads();
      }
    }
  }

  // ---- pipeline epilogue: act Q(1023) ----
  {
    const float hQ = act(accQ, cQ);
    hf[rowQ][jh] = hQ;
  }
  __syncthreads();

  // ---- out[b] = sigmoid(hT . fc_w + fc_b) ----
  if (tid < R) {
    float a = fc_b[0];
#pragma unroll
    for (int k = 0; k < 64; ++k) a += hf[tid][k] * fc_w[k];
    out[bBase + tid] = fsig(a);
  }
}
}  // namespace

extern "C" void kernel_launch(void* const* d_in, const int* in_sizes, int n_in,
                              void* d_out, int out_size, void* d_ws,
                              size_t ws_size, hipStream_t stream) {
  const float* x    = (const float*)d_in[0];
  const float* W_ih = (const float*)d_in[1];
  const float* W_hh = (const float*)d_in[2];
  const float* b_ih = (const float*)d_in[3];
  const float* b_hh = (const float*)d_in[4];
  const float* fc_w = (const float*)d_in[5];
  const float* fc_b = (const float*)d_in[6];
  float* out = (float*)d_out;

  const int B = in_sizes[0] / (T_LEN * 8);  // 2048
  lstm_pipe<<<dim3(B / R), dim3(256), 0, stream>>>(x, W_ih, W_hh, b_ih, b_hh,
                                                   fc_w, fc_b, out);
}

// Round 5
// 596.087 us; speedup vs baseline: 1.2934x; 1.2934x over previous
//
#include <hip/hip_runtime.h>

// LSTM (B=2048, T=1024, I=8, H=64) + sigmoid(FC), bf16 MFMA, in-register
// activations, duplicate-column split, 2 blocks/CU — r0 structure with a
// SHORTENED POST-BARRIER CHAIN.
//
// r1/r3/r4 lesson: the 2-blocks/CU r0 structure wins; structural pipelines
// (dual-chain, half-step P/Q, 1 block/CU) all regressed. This revision keeps
// r0 exactly and only shortens the per-step serial chain:
//  1. bias lives in the MFMA C-operand (bias4[g] per-thread constant), not a
//     K-slot, so the x-projection MFMA is seedable anywhere.
//  2. split accumulators: accA = x-seed + W_hh_lo*h_lo, accB = W_hh_hi*h_hi
//     issued in PARALLEL post-barrier (1-deep, was 3-deep serial); merged by
//     one add per gate at select time.
//  3. x-seed MFMAs for step t+1 issue PRE-barrier (after act reads accA,
//     WAR only). Chunk boundary (x buffer just restaged) defers the seed to
//     right after the barrier — compile-time branch under full unroll.
// Post-barrier chain: ds_read fh (~120cy) -> 1 MFMA (~35) -> select+add ->
// act (~130) -> ds_write. Was ~450cy, now ~315cy; two co-resident blocks
// cover each other's remainder.
//
// Verified keeps: HP=80 (bank conflicts 1.88e7->2.0e6), __expf + manual f2bf
// (exp2f lowers to slow ocml, r2: +22% VALU), plain __syncthreads (r1's raw
// s_barrier asm defeated the scheduler).

namespace {
constexpr int T_LEN = 1024;
constexpr int R     = 4;    // batch rows per block
constexpr int TS    = 32;   // timesteps of x per staged chunk
constexpr int HP    = 80;   // h_lds row stride in shorts (160 B, 16B-aligned)

typedef __attribute__((ext_vector_type(8))) short  short8v;
typedef __attribute__((ext_vector_type(4))) float  float4v;
typedef unsigned short u16;
typedef unsigned long long u64;

__device__ __forceinline__ float fsig(float x) {
  return __builtin_amdgcn_rcpf(1.f + __expf(-x));
}
__device__ __forceinline__ float ftanh(float x) {
  return 1.f - 2.f * __builtin_amdgcn_rcpf(__expf(2.f * x) + 1.f);
}
__device__ __forceinline__ u16 f2bf(float f) {  // RNE
  unsigned int u = __float_as_uint(f);
  unsigned int r = ((u >> 16) & 1u) + 0x7fffu;
  return (u16)((u + r) >> 16);
}

__global__ __launch_bounds__(256, 2) void lstm_split(
    const float* __restrict__ x,     // [B, T, 8]
    const float* __restrict__ W_ih,  // [256, 8]
    const float* __restrict__ W_hh,  // [256, 64]
    const float* __restrict__ b_ih,  // [256]
    const float* __restrict__ b_hh,  // [256]
    const float* __restrict__ fc_w,  // [64]
    const float* __restrict__ fc_b,  // [1]
    float* __restrict__ out) {       // [B]
  __shared__ __align__(16) u16   x_lds[2][TS][R][32];  // 16 KB; full K-rows
  __shared__ __align__(16) u16   h_lds[2][R][HP];      // 2.5 KB
  __shared__ __align__(16) float hf[R][64];            // final h (fp32)

  const int tid  = threadIdx.x;
  const int lane = tid & 63;
  const int wv   = tid >> 6;       // wave 0..3
  const int g4   = lane >> 4;      // MFMA k-quad / C row-quad
  const int nib  = lane & 15;      // MFMA m/n coord
  const int row  = nib & 3;        // batch row (cols 4..15 duplicate 0..3)
  const int rsel = nib >> 2;       // which acc reg this thread activates
  const int jh   = 16 * wv + 4 * g4 + rsel;  // owned h index
  const int bBase = blockIdx.x * R;

  // ---- static A fragments: wave wv holds tiles {4g+wv}, g=0..3 (i,f,g,o) ----
  // A[m=16*(4g+wv)+nib][k]; frag0 k=0..31 = [W_ih(8)|0...] (bias now in C),
  // frag1 = W_hh[:,0:32], frag2 = W_hh[:,32:64].
  short8v a0[4], a1[4], a2[4];
  float4v bias4[4];  // C-seed: bias for gate rows m = 64g+16wv+4g4+r, r=0..3
  for (int g = 0; g < 4; ++g) {
    const int n = 64 * g + 16 * wv + nib;  // A-fragment gate row
    short8v f0, f1, f2;
    for (int j = 0; j < 8; ++j) {
      const int k = 8 * g4 + j;
      float v0 = 0.f;
      if (k < 8) v0 = W_ih[n * 8 + k];
      f0[j] = (short)f2bf(v0);
      f1[j] = (short)f2bf(W_hh[n * 64 + k]);
      f2[j] = (short)f2bf(W_hh[n * 64 + 32 + k]);
    }
    a0[g] = f0; a1[g] = f1; a2[g] = f2;
    float4v b;
    for (int r = 0; r < 4; ++r) {
      const int m = 64 * g + 16 * wv + 4 * g4 + r;  // C row
      b[r] = b_ih[m] + b_hh[m];
    }
    bias4[g] = b;
  }

  // ---- LDS init: h0 = 0 (both bufs); x constant channels once per buf ----
  for (int i = tid; i < 2 * R * HP; i += 256) ((u16*)h_lds)[i] = 0;
  {  // 256 threads <-> 2 bufs x 32 tt x 4 rows
    const int buf = tid >> 7, rem = tid & 127, tt = rem >> 2, rr = rem & 3;
    u16* p = &x_lds[buf][tt][rr][0];
    for (int chn = 8; chn < 32; ++chn) p[chn] = 0;  // bias K-slot unused now
  }

  // ---- x staging: 1 float4/thread/chunk, double-buffered ----
  float4v xr;
  const int sr = tid >> 6, sm = tid & 63;          // src row, float4 idx
  const int stt = sm >> 1, sch = (sm & 1) * 4;     // dest tt, channel
  auto stage_load = [&](int chunk) {
    const float* src = x + ((size_t)bBase + sr) * (T_LEN * 8) +
                       (size_t)chunk * (TS * 8);
    xr = *(const float4v*)&src[sm * 4];
  };
  auto stage_write = [&](int buf) {
    union { u64 u; u16 s[4]; } p;
    p.s[0] = f2bf(xr[0]); p.s[1] = f2bf(xr[1]);
    p.s[2] = f2bf(xr[2]); p.s[3] = f2bf(xr[3]);
    *(u64*)&x_lds[buf][stt][sr][sch] = p.u;
  };

  stage_load(0);
  stage_write(0);
  __syncthreads();

  // hoisted select masks for the cndmask tree
  const bool sel1 = (rsel & 1) != 0;
  const bool sel2 = (rsel & 2) != 0;
  float c = 0.f;

  float4v accA[4], accB[4];
  auto seed_x = [&](const u16* xrow) {  // accA = W_ih * x + bias
    const short8v fx = *(const short8v*)(xrow + 8 * g4);
#pragma unroll
    for (int g = 0; g < 4; ++g)
      accA[g] = __builtin_amdgcn_mfma_f32_16x16x32_bf16(a0[g], fx, bias4[g],
                                                        0, 0, 0);
  };

  // ---- prologue: seed accA for t=0 ----
  seed_x(&x_lds[0][0][row][0]);

  for (int ch = 0; ch < T_LEN / TS; ++ch) {
    const int xb = ch & 1;
    const bool more = (ch < T_LEN / TS - 1);
#pragma unroll
    for (int tt = 0; tt < TS; ++tt) {
      const int t = ch * TS + tt;
      const int hb = t & 1;
      const bool last = (!more) && (tt == TS - 1);  // t == 1023
      if (tt == 0 && more) stage_load(ch + 1);  // reg loads; drain in stage_write

      // ---- post-barrier critical path: 2 parallel 1-deep MFMA chains ----
      const short8v fh0 = *(const short8v*)&h_lds[hb][row][8 * g4];
      const short8v fh1 = *(const short8v*)&h_lds[hb][row][32 + 8 * g4];
#pragma unroll
      for (int g = 0; g < 4; ++g) {
        accA[g] = __builtin_amdgcn_mfma_f32_16x16x32_bf16(a1[g], fh0, accA[g],
                                                          0, 0, 0);
        accB[g] = __builtin_amdgcn_mfma_f32_16x16x32_bf16(
            a2[g], fh1, (float4v){0.f, 0.f, 0.f, 0.f}, 0, 0, 0);
      }

      // ---- select this thread's element from both halves, merge, activate --
      float gsel[4];
#pragma unroll
      for (int g = 0; g < 4; ++g) {
        const float a01 = sel1 ? accA[g][1] : accA[g][0];
        const float a23 = sel1 ? accA[g][3] : accA[g][2];
        const float b01 = sel1 ? accB[g][1] : accB[g][0];
        const float b23 = sel1 ? accB[g][3] : accB[g][2];
        gsel[g] = (sel2 ? a23 : a01) + (sel2 ? b23 : b01);
      }
      const float iv = fsig(gsel[0]);
      const float fv = fsig(gsel[1]);
      const float gv = ftanh(gsel[2]);
      const float ov = fsig(gsel[3]);
      c = fv * c + iv * gv;
      const float h = ov * ftanh(c);
      h_lds[hb ^ 1][row][jh] = f2bf(h);
      if (last) hf[row][jh] = h;

      // ---- pre-barrier x-seed for t+1 (WAR on accA only) ----
      if (!last && tt < TS - 1) seed_x(&x_lds[xb][tt + 1][row][0]);
      if (tt == TS - 1 && more) stage_write(xb ^ 1);
      __syncthreads();  // one barrier per step
      // chunk boundary: buffer just restaged, seed after the barrier
      if (tt == TS - 1 && more) seed_x(&x_lds[xb ^ 1][0][row][0]);
    }
  }

  // ---- epilogue: out[b] = sigmoid(hT . fc_w + fc_b) ----
  if (tid < R) {
    float a = fc_b[0];
#pragma unroll
    for (int k = 0; k < 64; ++k) a += hf[tid][k] * fc_w[k];
    out[bBase + tid] = fsig(a);
  }
}
}  // namespace

extern "C" void kernel_launch(void* const* d_in, const int* in_sizes, int n_in,
                              void* d_out, int out_size, void* d_ws,
                              size_t ws_size, hipStream_t stream) {
  const float* x    = (const float*)d_in[0];
  const float* W_ih = (const float*)d_in[1];
  const float* W_hh = (const float*)d_in[2];
  const float* b_ih = (const float*)d_in[3];
  const float* b_hh = (const float*)d_in[4];
  const float* fc_w = (const float*)d_in[5];
  const float* fc_b = (const float*)d_in[6];
  float* out = (float*)d_out;

  const int B = in_sizes[0] / (T_LEN * 8);  // 2048
  lstm_split<<<dim3(B / R), dim3(256), 0, stream>>>(x, W_ih, W_hh, b_ih, b_hh,
                                                    fc_w, fc_b, out);
}